// Round 1
// baseline (271.360 us; speedup 1.0000x reference)
//
#include <hip/hip_runtime.h>

// BiLinearLayerV2: B=512, F=64, E=32
//   biLinear[b,f,d] = sum_e feature[b,f,e] * weight[f,e,d]
//   out[b,f,g,e]    = biLinear[b,f,e] * feature[b,g,e] * weightLeft[f,g]
// Output 256 MiB fp32 -> purely write-BW bound. One block per (b,f).

#define BDIM 512
#define FDIM 64
#define EDIM 32

__global__ __launch_bounds__(256) void bilinear_v2_kernel(
    const float* __restrict__ feature,    // [B,F,E]
    const float* __restrict__ weight,     // [F,E,E]
    const float* __restrict__ weightLeft, // [F,F]
    float* __restrict__ out)              // [B,F,F,E]
{
    const int bf = blockIdx.x;   // b*F + f
    const int f  = bf & (FDIM - 1);
    const int b  = bf >> 6;

    __shared__ float bl[EDIM];   // biLinear[b,f,:]
    __shared__ float wl[FDIM];   // weightLeft[f,:]

    const int t = threadIdx.x;

    // Lanes 0..31: compute biLinear row. Lanes 64..127: stage weightLeft row.
    if (t < EDIM) {
        const float* fp = feature + (size_t)bf * EDIM;        // feature[b,f,:]
        const float* wp = weight + (size_t)f * EDIM * EDIM;   // weight[f,:,:]
        float acc = 0.f;
        #pragma unroll
        for (int e = 0; e < EDIM; ++e) {
            acc += fp[e] * wp[e * EDIM + t];   // coalesced across t
        }
        bl[t] = acc;
    } else if (t >= 64 && t < 64 + FDIM) {
        wl[t - 64] = weightLeft[f * FDIM + (t - 64)];
    }
    __syncthreads();

    // Stream out[b,f,:,:] : F*E = 2048 floats = 512 float4, 256 threads x 2.
    float*       op = out     + (size_t)bf * (FDIM * EDIM);
    const float* fb = feature + (size_t)b  * (FDIM * EDIM);   // feature[b,:,:]

    #pragma unroll
    for (int i = 0; i < 2; ++i) {
        const int idx4 = t + i * 256;        // float4 index in [0,512)
        const int e4   = idx4 & (EDIM / 4 - 1);   // which float4 within the E row
        const int g    = idx4 >> 3;               // idx4 / (E/4)

        const float4 fv  = reinterpret_cast<const float4*>(fb)[idx4]; // feature[b,g,e..e+3]
        const float4 blv = reinterpret_cast<const float4*>(bl)[e4];   // LDS broadcast
        const float  w   = wl[g];                                     // LDS broadcast

        float4 o;
        o.x = blv.x * fv.x * w;
        o.y = blv.y * fv.y * w;
        o.z = blv.z * fv.z * w;
        o.w = blv.w * fv.w * w;
        reinterpret_cast<float4*>(op)[idx4] = o;
    }
}

extern "C" void kernel_launch(void* const* d_in, const int* in_sizes, int n_in,
                              void* d_out, int out_size, void* d_ws, size_t ws_size,
                              hipStream_t stream) {
    const float* feature    = (const float*)d_in[0];
    const float* weight     = (const float*)d_in[1];
    const float* weightLeft = (const float*)d_in[2];
    float* out = (float*)d_out;

    const int nblocks = BDIM * FDIM;   // 32768
    bilinear_v2_kernel<<<nblocks, 256, 0, stream>>>(feature, weight, weightLeft, out);
}

// Round 2
// 268.828 us; speedup vs baseline: 1.0094x; 1.0094x over previous
//
#include <hip/hip_runtime.h>

// BiLinearLayerV2: B=512, F=64, E=32
//   biLinear[b,f,d] = sum_e feature[b,f,e] * weight[f,e,d]
//   out[b,f,g,e]    = biLinear[b,f,e] * feature[b,g,e] * weightLeft[f,g]
// 268 MB fp32 output -> write-BW bound. One block per (b, group of 8 f's):
// 4096 blocks x 256 threads, 64 KiB of output per block (16 float4/thread).

#define BDIM 512
#define FDIM 64
#define EDIM 32
#define FPB  8                      // f rows per block
#define NFG  (FDIM / FPB)           // 8 f-groups per b

__global__ __launch_bounds__(256) void bilinear_v2_kernel(
    const float* __restrict__ feature,    // [B,F,E]
    const float* __restrict__ weight,     // [F,E,E]
    const float* __restrict__ weightLeft, // [F,F]
    float* __restrict__ out)              // [B,F,F,E]
{
    const int blk = blockIdx.x;             // b*NFG + fg
    const int fg  = blk & (NFG - 1);
    const int b   = blk >> 3;               // log2(NFG)=3
    const int f0  = fg * FPB;
    const int t   = threadIdx.x;

    __shared__ float s_feat[FDIM * EDIM];   // feature[b,:,:]   8 KiB
    __shared__ float s_bl[FPB * EDIM];      // biLinear rows    1 KiB
    __shared__ float s_wl[FPB * FDIM];      // weightLeft rows  2 KiB

    const float* fb = feature + (size_t)b * (FDIM * EDIM);

    // --- stage feature[b,:,:] : 512 float4, 2 per thread (coalesced) ---
    #pragma unroll
    for (int i = 0; i < 2; ++i) {
        const int idx = t + i * 256;
        reinterpret_cast<float4*>(s_feat)[idx] =
            reinterpret_cast<const float4*>(fb)[idx];
    }

    // --- stage weightLeft rows f0..f0+7 : 512 floats, 2 per thread ---
    #pragma unroll
    for (int i = 0; i < 2; ++i) {
        const int idx = t + i * 256;            // fl = idx>>6, g = idx&63
        s_wl[idx] = weightLeft[(f0 + (idx >> 6)) * FDIM + (idx & 63)];
    }

    // --- compute biLinear: thread -> (fl = t>>5, d = t&31), 32-MAC dot ---
    {
        const int fl = t >> 5;
        const int d  = t & 31;
        const int f  = f0 + fl;
        const float* fp = fb + f * EDIM;                          // broadcast reads
        const float* wp = weight + (size_t)f * EDIM * EDIM + d;   // coalesced over d
        float acc = 0.f;
        #pragma unroll
        for (int e = 0; e < EDIM; ++e)
            acc += fp[e] * wp[e * EDIM];
        s_bl[fl * EDIM + d] = acc;
    }
    __syncthreads();

    // --- stream out[b, f0..f0+7, :, :] : 4096 float4, 16 per thread ---
    float* op = out + ((size_t)b * FDIM + f0) * (FDIM * EDIM);

    #pragma unroll
    for (int i = 0; i < 16; ++i) {
        const int idx4 = t + i * 256;        // float4 index in [0,4096)
        const int e4   = idx4 & 7;           // float4 within E row
        const int g    = (idx4 >> 3) & 63;
        const int fl   = idx4 >> 9;

        // per-lane LDS addresses are linear in lane -> conflict-free
        const float4 fv  = reinterpret_cast<const float4*>(s_feat)[g * 8 + e4];
        const float4 blv = reinterpret_cast<const float4*>(s_bl)[fl * 8 + e4];
        const float  w   = s_wl[fl * 64 + g];

        float4 o;
        o.x = blv.x * fv.x * w;
        o.y = blv.y * fv.y * w;
        o.z = blv.z * fv.z * w;
        o.w = blv.w * fv.w * w;
        reinterpret_cast<float4*>(op)[idx4] = o;
    }
}

extern "C" void kernel_launch(void* const* d_in, const int* in_sizes, int n_in,
                              void* d_out, int out_size, void* d_ws, size_t ws_size,
                              hipStream_t stream) {
    const float* feature    = (const float*)d_in[0];
    const float* weight     = (const float*)d_in[1];
    const float* weightLeft = (const float*)d_in[2];
    float* out = (float*)d_out;

    const int nblocks = BDIM * NFG;   // 4096
    bilinear_v2_kernel<<<nblocks, 256, 0, stream>>>(feature, weight, weightLeft, out);
}